// Round 1
// 83.981 us; speedup vs baseline: 1.1306x; 1.1306x over previous
//
#include <hip/hip_runtime.h>
#include <hip/hip_bf16.h>

#define B_ROWS 4096
#define N_ROWS 8192
#define D 128
#define SCALE 2.885390081777927f   // (1/temperature) * log2(e) = 2 * 1.4426950408889634
#define LN2 0.6931471805599453f

#define TB 128                     // triangular tile dim
#define NB (N_ROWS / TB)           // 64 row-blocks
#define NBLK (NB * (NB / 2) + NB / 2)   // 64*32 + 32 = 2080 unordered pairs incl. diagonal

typedef __attribute__((ext_vector_type(8))) short bf16x8;
typedef __attribute__((ext_vector_type(4))) float f32x4;

__device__ inline unsigned short f32_to_bf16_rne(float f) {
    unsigned int u = __float_as_uint(f);
    u += 0x7fffu + ((u >> 16) & 1u);   // round-to-nearest-even (no NaNs here)
    return (unsigned short)(u >> 16);
}
__device__ inline float bf16s_to_f32(short s) {
    unsigned int u = ((unsigned int)(unsigned short)s) << 16;
    return __uint_as_float(u);
}

// ---------------- Kernel 1: row-normalize fp32 -> bf16 (+ zero denom/out) ----
// 256-thread blocks, one wave per row, 4 rows/block. First 32 blocks also
// zero the denominator array; block 0 zeroes the scalar output. Stream order
// makes these visible to k_simsum / k_finalize — no memset nodes needed.
__global__ void k_normalize(const float* __restrict__ z_i,
                            const float* __restrict__ z_j,
                            unsigned short* __restrict__ zn,
                            float* __restrict__ denom,
                            float* __restrict__ out) {
    if (blockIdx.x < 32) denom[blockIdx.x * 256 + threadIdx.x] = 0.f;
    if (blockIdx.x == 0 && threadIdx.x == 0) out[0] = 0.f;

    int row  = blockIdx.x * 4 + (threadIdx.x >> 6);
    int lane = threadIdx.x & 63;
    const float* src = (row < B_ROWS) ? (z_i + (size_t)row * D)
                                      : (z_j + (size_t)(row - B_ROWS) * D);
    float2 v = ((const float2*)src)[lane];
    float ss = v.x * v.x + v.y * v.y;
    #pragma unroll
    for (int m = 1; m < 64; m <<= 1) ss += __shfl_xor(ss, m);
    float rinv = 1.0f / fmaxf(sqrtf(ss), 1e-8f);
    ushort2 o;
    o.x = f32_to_bf16_rne(v.x * rinv);
    o.y = f32_to_bf16_rne(v.y * rinv);
    ((ushort2*)(zn + (size_t)row * D))[lane] = o;
}

// ---------------- Kernel 2: symmetric sim-GEMM + exp + row/col sums ----------
// The sim matrix is exactly symmetric (bitwise: same f32 MFMA dot, same K
// order), so we enumerate only unordered pairs of 128-row blocks (2080 of
// them). Off-diagonal tiles credit exp(s) to BOTH denom[row] (row-sum in
// registers) and denom[col] (col-sum via in-lane + quad shfl reduce, staged
// per-wave in LDS, one global atomic per column per block). Diagonal tiles
// credit row-sums only. Entry count: 34.1M vs 64M for the full sweep.
//
// Pair enumeration: t<2048: bx=t&63, by=t>>6 (offset 0..31); t>=2048: by=32,
// bx=t-2048 (0..31). (bi,bj)=(bx,(bx+by)&63) hits every unordered pair once.
//
// B strip (zn rows c0..c0+127) staged in LDS with the XOR-swizzled 16B-piece
// layout: piece(c, j) stored at index c*16 + (j ^ (c & 7)).
__global__ __launch_bounds__(256, 2)
void k_simsum(const unsigned short* __restrict__ zn,
              float* __restrict__ denom) {
    __shared__ unsigned short sB[TB * 16 * 8];   // 32 KB
    __shared__ float csum[4][TB];                // 2 KB

    int t = blockIdx.x;
    int bx, by;
    if (t < NB * (NB / 2)) { bx = t & (NB - 1); by = t >> 6; }
    else                   { bx = t - NB * (NB / 2); by = NB / 2; }
    const int bi   = bx;
    const int bj   = (bx + by) & (NB - 1);
    const bool diag = (by == 0);

    const int tid  = threadIdx.x;
    const int wave = tid >> 6;
    const int lane = tid & 63;
    const int l15  = lane & 15;
    const int quad = lane >> 4;

    const int r0 = bi * TB + wave * 32;   // this wave's 32 rows
    const int c0 = bj * TB;               // block's 128 columns

    // issue the B-strip loads first (consumed soonest, by the ds_writes)
    float4 st[8];
    #pragma unroll
    for (int p = 0; p < 8; ++p) {
        int i = tid + p * 256, c = i >> 4, j = i & 15;
        st[p] = *(const float4*)(zn + (size_t)(c0 + c) * D + j * 8);
    }

    // A fragments: 2 row-tiles x 4 k-blocks, registers for the whole sweep
    bf16x8 A[2][4];
    #pragma unroll
    for (int rt = 0; rt < 2; ++rt)
        #pragma unroll
        for (int kb = 0; kb < 4; ++kb)
            A[rt][kb] = *(const bf16x8*)(zn + (size_t)(r0 + rt * 16 + l15) * D + kb * 32 + quad * 8);

    #pragma unroll
    for (int p = 0; p < 8; ++p) {
        int i = tid + p * 256, c = i >> 4, j = i & 15;
        int piece = c * 16 + (j ^ (c & 7));
        *(float4*)(sB + piece * 8) = st[p];
    }

    float rs[2][4];
    #pragma unroll
    for (int rt = 0; rt < 2; ++rt)
        #pragma unroll
        for (int j = 0; j < 4; ++j) rs[rt][j] = 0.f;

    __syncthreads();

    #pragma unroll
    for (int ct = 0; ct < TB / 16; ++ct) {   // 8 col-tiles of 16
        bf16x8 b[4];
        #pragma unroll
        for (int kb = 0; kb < 4; ++kb) {
            int c = ct * 16 + l15;
            int piece = c * 16 + ((kb * 4 + quad) ^ (c & 7));
            b[kb] = *(const bf16x8*)(sB + piece * 8);
        }
        f32x4 acc[2];
        #pragma unroll
        for (int rt = 0; rt < 2; ++rt) acc[rt] = (f32x4){0.f, 0.f, 0.f, 0.f};
        #pragma unroll
        for (int kb = 0; kb < 4; ++kb)
            #pragma unroll
            for (int rt = 0; rt < 2; ++rt)
                acc[rt] = __builtin_amdgcn_mfma_f32_16x16x32_bf16(A[rt][kb], b[kb], acc[rt], 0, 0, 0);

        float cs = 0.f;
        #pragma unroll
        for (int rt = 0; rt < 2; ++rt)
            #pragma unroll
            for (int j = 0; j < 4; ++j) {
                float e = __builtin_amdgcn_exp2f(acc[rt][j] * SCALE);
                rs[rt][j] += e;
                cs += e;
            }
        if (!diag) {
            // column-sum over the 16 rows of this tile: in-lane (rt,j) done,
            // now across the 4 quad groups (lanes ^16, ^32)
            cs += __shfl_xor(cs, 16);
            cs += __shfl_xor(cs, 32);
            if (quad == 0) csum[wave][ct * 16 + l15] = cs;
        }
    }

    // row-sums: reduce across the 16 column-lanes, one atomic per row
    #pragma unroll
    for (int rt = 0; rt < 2; ++rt)
        #pragma unroll
        for (int j = 0; j < 4; ++j) {
            float v = rs[rt][j];
            v += __shfl_xor(v, 1);
            v += __shfl_xor(v, 2);
            v += __shfl_xor(v, 4);
            v += __shfl_xor(v, 8);
            rs[rt][j] = v;
        }
    if (l15 == 0) {
        #pragma unroll
        for (int rt = 0; rt < 2; ++rt)
            #pragma unroll
            for (int j = 0; j < 4; ++j)
                atomicAdd(&denom[r0 + rt * 16 + quad * 4 + j], rs[rt][j]);
    }

    // column-sums: combine the 4 waves' partials, one atomic per column
    if (!diag) {
        __syncthreads();
        if (tid < TB) {
            float s = csum[0][tid] + csum[1][tid] + csum[2][tid] + csum[3][tid];
            atomicAdd(&denom[c0 + tid], s);
        }
    }
}

// ---------------- Kernel 3: per-row loss + mean reduce ----------------
__global__ void k_finalize(const unsigned short* __restrict__ zn,
                           const float* __restrict__ denom,
                           float* __restrict__ out) {
    int i = blockIdx.x * blockDim.x + threadIdx.x;
    int p = (i + B_ROWS) & (N_ROWS - 1);
    const unsigned short* zi = zn + (size_t)i * D;
    const unsigned short* zp = zn + (size_t)p * D;
    float self_dot = 0.f, pos_dot = 0.f;
    #pragma unroll
    for (int c = 0; c < D / 8; ++c) {
        bf16x8 a = *(const bf16x8*)(zi + c * 8);
        bf16x8 b = *(const bf16x8*)(zp + c * 8);
        #pragma unroll
        for (int j = 0; j < 8; ++j) {
            float av = bf16s_to_f32(a[j]);
            float bv = bf16s_to_f32(b[j]);
            self_dot += av * av;
            pos_dot  += av * bv;
        }
    }
    // denom included self and pos terms; subtract self (same exp2 arithmetic).
    float dnm  = denom[i] - __builtin_amdgcn_exp2f(self_dot * SCALE);
    float loss = __builtin_amdgcn_logf(dnm) * LN2 - pos_dot * 2.0f;  // -log(pos/denom)

    float v = loss;
    #pragma unroll
    for (int m = 1; m < 64; m <<= 1) v += __shfl_xor(v, m);
    __shared__ float ws[4];
    int wave = threadIdx.x >> 6;
    if ((threadIdx.x & 63) == 0) ws[wave] = v;
    __syncthreads();
    if (threadIdx.x == 0) {
        float s = ws[0] + ws[1] + ws[2] + ws[3];
        atomicAdd(out, s * (1.0f / (float)N_ROWS));
    }
}

extern "C" void kernel_launch(void* const* d_in, const int* in_sizes, int n_in,
                              void* d_out, int out_size, void* d_ws, size_t ws_size,
                              hipStream_t stream) {
    const float* z_i = (const float*)d_in[0];
    const float* z_j = (const float*)d_in[1];
    float* out = (float*)d_out;

    unsigned short* zn = (unsigned short*)d_ws;                      // N*D bf16 = 2 MB
    float* denom = (float*)((char*)d_ws + (size_t)N_ROWS * D * 2);   // N fp32 = 32 KB

    k_normalize<<<N_ROWS / 4, 256, 0, stream>>>(z_i, z_j, zn, denom, out);
    k_simsum<<<NBLK, 256, 0, stream>>>(zn, denom);
    k_finalize<<<N_ROWS / 256, 256, 0, stream>>>(zn, denom, out);
}

// Round 3
// 83.584 us; speedup vs baseline: 1.1360x; 1.0048x over previous
//
#include <hip/hip_runtime.h>
#include <hip/hip_bf16.h>

#define B_ROWS 4096
#define N_ROWS 8192
#define D 128
#define SCALE 2.885390081777927f        // (1/temperature) * log2(e) = 2 * 1.4426950408889634
#define SQRT_SCALE 1.69864360f          // sqrt(SCALE); zn is pre-scaled by this
#define LN2 0.6931471805599453f

#define TB 128                     // triangular tile dim
#define NB (N_ROWS / TB)           // 64 row-blocks
#define NBLK (NB * (NB / 2) + NB / 2)   // 64*32 + 32 = 2080 unordered pairs incl. diagonal

typedef __attribute__((ext_vector_type(8))) short bf16x8;
typedef __attribute__((ext_vector_type(4))) float f32x4;

__device__ inline unsigned short f32_to_bf16_rne(float f) {
    unsigned int u = __float_as_uint(f);
    u += 0x7fffu + ((u >> 16) & 1u);   // round-to-nearest-even (no NaNs here)
    return (unsigned short)(u >> 16);
}
__device__ inline float bf16s_to_f32(short s) {
    unsigned int u = ((unsigned int)(unsigned short)s) << 16;
    return __uint_as_float(u);
}

// ---------------- Kernel 1: row-normalize fp32 -> bf16 (+ zero denom/out) ----
// 256-thread blocks, one wave per row, 4 rows/block. Rows are normalized AND
// pre-scaled by sqrt(SCALE), so the sim-GEMM's dot product comes out already
// multiplied by SCALE (saves one v_mul per sim entry). First 32 blocks also
// zero the denominator array; block 0 zeroes the scalar output. Stream order
// makes these visible to k_simsum / k_finalize — no memset nodes needed.
__global__ void k_normalize(const float* __restrict__ z_i,
                            const float* __restrict__ z_j,
                            unsigned short* __restrict__ zn,
                            float* __restrict__ denom,
                            float* __restrict__ out) {
    if (blockIdx.x < 32) denom[blockIdx.x * 256 + threadIdx.x] = 0.f;
    if (blockIdx.x == 0 && threadIdx.x == 0) out[0] = 0.f;

    int row  = blockIdx.x * 4 + (threadIdx.x >> 6);
    int lane = threadIdx.x & 63;
    const float* src = (row < B_ROWS) ? (z_i + (size_t)row * D)
                                      : (z_j + (size_t)(row - B_ROWS) * D);
    float2 v = ((const float2*)src)[lane];
    float ss = v.x * v.x + v.y * v.y;
    #pragma unroll
    for (int m = 1; m < 64; m <<= 1) ss += __shfl_xor(ss, m);
    float rinv = SQRT_SCALE / fmaxf(sqrtf(ss), 1e-8f);
    ushort2 o;
    o.x = f32_to_bf16_rne(v.x * rinv);
    o.y = f32_to_bf16_rne(v.y * rinv);
    ((ushort2*)(zn + (size_t)row * D))[lane] = o;
}

// ---------------- Kernel 2: symmetric sim-GEMM + exp + row/col sums ----------
// The sim matrix is exactly symmetric (bitwise: same f32 MFMA dot, same K
// order), so we enumerate only unordered pairs of 128-row blocks (2080 of
// them). Off-diagonal tiles credit exp2(s) to BOTH denom[row] (row-sum in
// registers) and denom[col] (col-sum via in-lane + quad shfl reduce, staged
// per-wave in LDS, one global atomic per column per block). Diagonal tiles
// credit row-sums only. Entry count: 34.1M vs 64M for the full sweep.
//
// Pair enumeration: t<2048: bx=t&63, by=t>>6 (offset 0..31); t>=2048: by=32,
// bx=t-2048 (0..31). (bi,bj)=(bx,(bx+by)&63) hits every unordered pair once.
//
// B strip (zn rows c0..c0+127) staged in LDS with the XOR-swizzled 16B-piece
// layout: piece(c, j) stored at index c*16 + (j ^ (c & 7)), j = 16B-chunk
// within row. Register-staged (proven path; staging is once per block, cheap).
__global__ __launch_bounds__(256, 3)
void k_simsum(const unsigned short* __restrict__ zn,
              float* __restrict__ denom) {
    __shared__ unsigned short sB[TB * 16 * 8];   // 32 KB
    __shared__ float csum[4][TB];                // 2 KB

    int t = blockIdx.x;
    int bx, by;
    if (t < NB * (NB / 2)) { bx = t & (NB - 1); by = t >> 6; }
    else                   { bx = t - NB * (NB / 2); by = NB / 2; }
    const int bi   = bx;
    const int bj   = (bx + by) & (NB - 1);
    const bool diag = (by == 0);

    const int tid  = threadIdx.x;
    const int wave = tid >> 6;
    const int lane = tid & 63;
    const int l15  = lane & 15;
    const int quad = lane >> 4;

    const int r0 = bi * TB + wave * 32;   // this wave's 32 rows
    const int c0 = bj * TB;               // block's 128 columns

    // issue the B-strip loads first (consumed soonest, by the ds_writes)
    float4 st[8];
    #pragma unroll
    for (int p = 0; p < 8; ++p) {
        int i = tid + p * 256, c = i >> 4, j = i & 15;
        st[p] = *(const float4*)(zn + (size_t)(c0 + c) * D + j * 8);
    }

    // A fragments: 2 row-tiles x 4 k-blocks, registers for the whole sweep
    bf16x8 A[2][4];
    #pragma unroll
    for (int rt = 0; rt < 2; ++rt)
        #pragma unroll
        for (int kb = 0; kb < 4; ++kb)
            A[rt][kb] = *(const bf16x8*)(zn + (size_t)(r0 + rt * 16 + l15) * D + kb * 32 + quad * 8);

    #pragma unroll
    for (int p = 0; p < 8; ++p) {
        int i = tid + p * 256, c = i >> 4, j = i & 15;
        int piece = c * 16 + (j ^ (c & 7));
        *(float4*)(sB + piece * 8) = st[p];
    }

    float rs[2][4];
    #pragma unroll
    for (int rt = 0; rt < 2; ++rt)
        #pragma unroll
        for (int j = 0; j < 4; ++j) rs[rt][j] = 0.f;

    __syncthreads();

    #pragma unroll
    for (int ct = 0; ct < TB / 16; ++ct) {   // 8 col-tiles of 16
        bf16x8 b[4];
        #pragma unroll
        for (int kb = 0; kb < 4; ++kb) {
            int c = ct * 16 + l15;
            int piece = c * 16 + ((kb * 4 + quad) ^ (c & 7));
            b[kb] = *(const bf16x8*)(sB + piece * 8);
        }
        f32x4 acc[2];
        #pragma unroll
        for (int rt = 0; rt < 2; ++rt) acc[rt] = (f32x4){0.f, 0.f, 0.f, 0.f};
        #pragma unroll
        for (int kb = 0; kb < 4; ++kb)
            #pragma unroll
            for (int rt = 0; rt < 2; ++rt)
                acc[rt] = __builtin_amdgcn_mfma_f32_16x16x32_bf16(A[rt][kb], b[kb], acc[rt], 0, 0, 0);

        float cs = 0.f;
        #pragma unroll
        for (int rt = 0; rt < 2; ++rt)
            #pragma unroll
            for (int j = 0; j < 4; ++j) {
                float e = __builtin_amdgcn_exp2f(acc[rt][j]);   // dot is pre-scaled
                rs[rt][j] += e;
                cs += e;
            }
        if (!diag) {
            // column-sum over the 16 rows of this tile: in-lane (rt,j) done,
            // now across the 4 quad groups (lanes ^16, ^32)
            cs += __shfl_xor(cs, 16);
            cs += __shfl_xor(cs, 32);
            if (quad == 0) csum[wave][ct * 16 + l15] = cs;
        }
    }

    // row-sums: reduce across the 16 column-lanes, one atomic per row
    #pragma unroll
    for (int rt = 0; rt < 2; ++rt)
        #pragma unroll
        for (int j = 0; j < 4; ++j) {
            float v = rs[rt][j];
            v += __shfl_xor(v, 1);
            v += __shfl_xor(v, 2);
            v += __shfl_xor(v, 4);
            v += __shfl_xor(v, 8);
            rs[rt][j] = v;
        }
    if (l15 == 0) {
        #pragma unroll
        for (int rt = 0; rt < 2; ++rt)
            #pragma unroll
            for (int j = 0; j < 4; ++j)
                atomicAdd(&denom[r0 + rt * 16 + quad * 4 + j], rs[rt][j]);
    }

    // column-sums: combine the 4 waves' partials, one atomic per column
    if (!diag) {
        __syncthreads();
        if (tid < TB) {
            float s = csum[0][tid] + csum[1][tid] + csum[2][tid] + csum[3][tid];
            atomicAdd(&denom[c0 + tid], s);
        }
    }
}

// ---------------- Kernel 3: per-row loss + mean reduce ----------------
__global__ void k_finalize(const unsigned short* __restrict__ zn,
                           const float* __restrict__ denom,
                           float* __restrict__ out) {
    int i = blockIdx.x * blockDim.x + threadIdx.x;
    int p = (i + B_ROWS) & (N_ROWS - 1);
    const unsigned short* zi = zn + (size_t)i * D;
    const unsigned short* zp = zn + (size_t)p * D;
    float self_dot = 0.f, pos_dot = 0.f;
    #pragma unroll
    for (int c = 0; c < D / 8; ++c) {
        bf16x8 a = *(const bf16x8*)(zi + c * 8);
        bf16x8 b = *(const bf16x8*)(zp + c * 8);
        #pragma unroll
        for (int j = 0; j < 8; ++j) {
            float av = bf16s_to_f32(a[j]);
            float bv = bf16s_to_f32(b[j]);
            self_dot += av * av;
            pos_dot  += av * bv;
        }
    }
    // zn is pre-scaled by sqrt(SCALE): dots are already SCALE * cos-sim.
    // denom included self and pos terms; subtract self (same exp2 arithmetic).
    float dnm  = denom[i] - __builtin_amdgcn_exp2f(self_dot);
    // -log(pos/denom) = ln(denom) - sim/T = (log2(denom) - pos_dot_scaled)*ln2
    float loss = (__builtin_amdgcn_logf(dnm) - pos_dot) * LN2;

    float v = loss;
    #pragma unroll
    for (int m = 1; m < 64; m <<= 1) v += __shfl_xor(v, m);
    __shared__ float ws[4];
    int wave = threadIdx.x >> 6;
    if ((threadIdx.x & 63) == 0) ws[wave] = v;
    __syncthreads();
    if (threadIdx.x == 0) {
        float s = ws[0] + ws[1] + ws[2] + ws[3];
        atomicAdd(out, s * (1.0f / (float)N_ROWS));
    }
}

extern "C" void kernel_launch(void* const* d_in, const int* in_sizes, int n_in,
                              void* d_out, int out_size, void* d_ws, size_t ws_size,
                              hipStream_t stream) {
    const float* z_i = (const float*)d_in[0];
    const float* z_j = (const float*)d_in[1];
    float* out = (float*)d_out;

    unsigned short* zn = (unsigned short*)d_ws;                      // N*D bf16 = 2 MB
    float* denom = (float*)((char*)d_ws + (size_t)N_ROWS * D * 2);   // N fp32 = 32 KB

    k_normalize<<<N_ROWS / 4, 256, 0, stream>>>(z_i, z_j, zn, denom, out);
    k_simsum<<<NBLK, 256, 0, stream>>>(zn, denom);
    k_finalize<<<N_ROWS / 256, 256, 0, stream>>>(zn, denom, out);
}